// Round 19
// baseline (153.226 us; speedup 1.0000x reference)
//
#include <hip/hip_runtime.h>
#include <hip/hip_bf16.h>

#define B_ 2
#define C_ 256
#define H_ 64
#define W_ 64
#define N_ 4096  // H_*W_

typedef short bf16x8 __attribute__((ext_vector_type(8)));
typedef _Float16 f16x8 __attribute__((ext_vector_type(8)));
typedef float f32x4 __attribute__((ext_vector_type(4)));
typedef float f32x16 __attribute__((ext_vector_type(16)));

// float -> bf16 (round to nearest even), finite inputs
static __device__ __forceinline__ unsigned short f2bf(float f) {
    union { float f; unsigned u; } uf; uf.f = f;
    unsigned r = uf.u + 0x7fffu + ((uf.u >> 16) & 1u);
    return (unsigned short)(r >> 16);
}
// bf16 bits -> float
static __device__ __forceinline__ float bf2f(unsigned short us) {
    union { unsigned u; float f; } c; c.u = ((unsigned)us) << 16; return c.f;
}
// float -> fp16 bits
static __device__ __forceinline__ unsigned short f2h_u(float f) {
    union { _Float16 h; unsigned short u; } c; c.h = (_Float16)f; return c.u;
}

// async global->LDS, 16B per lane. LDS dest must be wave-uniform base + lane*16.
static __device__ __forceinline__ void gload16(const void* g, void* l) {
    __builtin_amdgcn_global_load_lds(
        (const __attribute__((address_space(1))) unsigned int*)g,
        (__attribute__((address_space(3))) unsigned int*)l, 16, 0, 0);
}

// ---------------------------------------------------------------------------
// Prep (merged): blocks [0,1024): [B][C][N] f32 -> [B][N][C] fp16 transpose
// for x and ref_x; blocks [1024,5632): both weights -> [tap][O][I] fp16.
// ---------------------------------------------------------------------------
__global__ __launch_bounds__(256) void prep_k(
    const float* __restrict__ x, const float* __restrict__ ref_x,
    const float* __restrict__ w1, const float* __restrict__ w2,
    unsigned short* __restrict__ xtx, unsigned short* __restrict__ xtr,
    unsigned short* __restrict__ wh1, unsigned short* __restrict__ wh2)
{
    __shared__ unsigned short t[64][72];
    const int bx = blockIdx.x;
    if (bx < 1024) {
        const int pt = bx & 63, ct = (bx >> 6) & 3;
        const int z = bx >> 8;
        const int which = z >> 1, b = z & 1;
        const float* in = which ? ref_x : x;
        unsigned short* out = which ? xtr : xtx;
        const int a = threadIdx.x & 63, r = threadIdx.x >> 6;
        #pragma unroll
        for (int i = 0; i < 16; ++i) {
            int c = i * 4 + r;
            t[c][a] = f2h_u(in[((size_t)(b * C_ + ct * 64 + c) << 12) + pt * 64 + a]);
        }
        __syncthreads();
        #pragma unroll
        for (int i = 0; i < 16; ++i) {
            int p = i * 4 + r;
            out[((size_t)(b * N_ + pt * 64 + p) << 8) + ct * 64 + a] = t[a][p];
        }
    } else {
        int g = bx - 1024;
        const float* w = (g < 2304) ? w1 : w2;
        unsigned short* wh = (g < 2304) ? wh1 : wh2;
        int i = (g % 2304) * 256 + threadIdx.x;     // < 9*256*256 exactly
        int ci = i & 255, co = (i >> 8) & 255, tap = i >> 16;
        wh[i] = f2h_u(w[((size_t)(co * 256 + ci)) * 9 + tap]);
    }
}

// ---------------------------------------------------------------------------
// Implicit-GEMM 3x3 SAME conv + bias + relu via MFMA fp16 (r4-proven version).
// ---------------------------------------------------------------------------
__global__ __launch_bounds__(256) void conv_mfma_k(
    const unsigned short* __restrict__ xtx, const unsigned short* __restrict__ xtr,
    const unsigned short* __restrict__ w1h, const unsigned short* __restrict__ w2h,
    const float* __restrict__ b1, const float* __restrict__ b2,
    unsigned short* __restrict__ f1x, unsigned short* __restrict__ f1r,
    unsigned short* __restrict__ f2)
{
    __shared__ unsigned short As[4 * 576 * 8];   // (q*576 + tap*64 + co)*8
    __shared__ unsigned short Bs[4 * 66 * 32];   // [row][col(pad)][ci-chunk swz]
    const int tid = threadIdx.x;
    const int pt  = blockIdx.x;   // 0..31 : plane rows pt*2, pt*2+1
    const int cot = blockIdx.y;   // 0..3
    const int cid = blockIdx.z >> 1;
    const int b   = blockIdx.z & 1;

    const unsigned short* xt = (cid == 1) ? xtr : xtx;
    const unsigned short* wt = (cid == 2) ? w2h : w1h;
    const float* bias = (cid == 2) ? b2 : b1;
    unsigned short* out = (cid == 0) ? f1x : (cid == 1) ? f1r : f2;
    const int trans = (cid != 2);

    const int lane = tid & 63, wid = tid >> 6;
    const int wco = wid >> 1, wpos = wid & 1;
    const int rl = lane & 15, q = lane >> 4;
    const int r0 = pt * 2;

    f32x4 acc[2][4];
    #pragma unroll
    for (int mi = 0; mi < 2; ++mi)
        #pragma unroll
        for (int ni = 0; ni < 4; ++ni)
            #pragma unroll
            for (int e = 0; e < 4; ++e) acc[mi][ni][e] = 0.f;

    for (int k0 = 0; k0 < C_; k0 += 32) {
        #pragma unroll
        for (int tap = 0; tap < 9; ++tap) {
            gload16(wt + ((size_t)(tap * C_ + cot * 64 + lane) << 8) + k0 + wid * 8,
                    &As[(wid * 576 + tap * 64 + lane) * 8]);
        }
        #pragma unroll
        for (int j = 0; j < 5; ++j) {
            int it = tid + j * 256;
            if (it < 1056) {
                int col = it >> 4, sub = it & 15;
                int row = sub >> 2, qb = sub & 3;
                int h = r0 + row - 1, c = col - 1;
                float4 v; v.x = 0.f; v.y = 0.f; v.z = 0.f; v.w = 0.f;
                if (h >= 0 && h < 64 && c >= 0 && c < 64)
                    v = *(const float4*)(xt + ((size_t)(b * N_ + h * 64 + c) << 8) + k0 + qb * 8);
                int chunk = qb ^ ((col >> 1) & 3);
                *(float4*)&Bs[(row * 66 + col) * 32 + chunk * 8] = v;
            }
        }
        __syncthreads();

        #pragma unroll
        for (int tap = 0; tap < 9; ++tap) {
            const int kh = tap / 3, kw = tap % 3;
            f16x8 a0 = *(const f16x8*)&As[(q * 576 + tap * 64 + wco * 32 + rl) * 8];
            f16x8 a1 = *(const f16x8*)&As[(q * 576 + tap * 64 + wco * 32 + 16 + rl) * 8];
            const int chunkB = q ^ (((rl + kw) >> 1) & 3);
            const int rowB = (wpos + kh) * 66;
            #pragma unroll
            for (int ni = 0; ni < 4; ++ni) {
                int colB = ni * 16 + rl + kw;
                f16x8 bf = *(const f16x8*)&Bs[(rowB + colB) * 32 + chunkB * 8];
                acc[0][ni] = __builtin_amdgcn_mfma_f32_16x16x32_f16(a0, bf, acc[0][ni], 0, 0, 0);
                acc[1][ni] = __builtin_amdgcn_mfma_f32_16x16x32_f16(a1, bf, acc[1][ni], 0, 0, 0);
            }
        }
        __syncthreads();
    }

    #pragma unroll
    for (int mi = 0; mi < 2; ++mi) {
        const int co = cot * 64 + wco * 32 + mi * 16 + q * 4;
        float bs[4];
        #pragma unroll
        for (int rr = 0; rr < 4; ++rr) bs[rr] = bias[co + rr];
        #pragma unroll
        for (int ni = 0; ni < 4; ++ni) {
            const int pos = pt * 128 + wpos * 64 + ni * 16 + rl;
            if (trans) {
                unsigned short pk[4];
                #pragma unroll
                for (int rr = 0; rr < 4; ++rr)
                    pk[rr] = f2bf(fmaxf(acc[mi][ni][rr] + bs[rr], 0.f));
                uint2 u;
                u.x = (unsigned)pk[0] | ((unsigned)pk[1] << 16);
                u.y = (unsigned)pk[2] | ((unsigned)pk[3] << 16);
                *(uint2*)&out[((size_t)(b * N_ + pos) << 8) + co] = u;
            } else {
                #pragma unroll
                for (int rr = 0; rr < 4; ++rr)
                    out[((size_t)(b * C_ + co + rr) << 12) + pos] =
                        f2bf(fmaxf(acc[mi][ni][rr] + bs[rr], 0.f));
            }
        }
    }
}

// ---------------------------------------------------------------------------
// Flash attention v4: KVBLK=32, 128-thr blocks, 4 blocks/CU + V read DIRECT
// from global (L2-resident 512KB slab shared by 128 blocks — m169 pattern:
// LDS-staging L2-fit data is pure overhead). Removes V ds_writes (the 4.19M
// bank-conflict source) and halves LDS to 16.9 KB. K stays LDS-staged
// (16x reuse/wave). Same per-lane values as v3 -> bit-identical math.
// Grid (128 mt, 4 s, 2 b) = 1024 blocks. se = s -> 4 partials (bf16).
// ---------------------------------------------------------------------------
__global__ __launch_bounds__(128, 2) void flash_k(
    const unsigned short* __restrict__ f1x,  // Q  [b][m][ch] bf16
    const unsigned short* __restrict__ f1r,  // K  [b][n][ch] bf16
    const unsigned short* __restrict__ f2,   // V^T [b][c][n] bf16
    unsigned short* __restrict__ part,       // [4][B][C][N] bf16
    float* __restrict__ stats)               // float2 [4][B][N]
{
    __shared__ unsigned short Ks[32 * 264];  // [n32][256ch + 8 pad]
    const int tid = threadIdx.x;             // 0..127
    const int mt = blockIdx.x, s = blockIdx.y, b = blockIdx.z;
    const int m0 = mt * 32;
    const int lane = tid & 63, wc2 = tid >> 6;
    const int rl = lane & 31, l5 = lane >> 5;
    const int c0w = wc2 * 128;

    // Q B-frags for 16 ch-steps (row m = rl, k = l5*8+j)
    bf16x8 Qf[16];
    #pragma unroll
    for (int st = 0; st < 16; ++st)
        Qf[st] = *(const bf16x8*)&f1x[(((size_t)b * N_ + m0 + rl) << 8) + st * 16 + l5 * 8];

    // per-lane V row base pointers (c = c0w + cf*32 + rl), row stride 4096
    const unsigned short* vbase = f2 + (((size_t)b * C_ + c0w + rl) << 12);

    f32x16 O[4];
    #pragma unroll
    for (int cf = 0; cf < 4; ++cf)
        #pragma unroll
        for (int e = 0; e < 16; ++e) O[cf][e] = 0.f;
    float m_run = -1e30f, l_run = 0.f;

    const int nbase = s * 1024;
    for (int r = 0; r < 32; ++r) {
        const int n0 = nbase + r * 32;
        // stage K: 32 rows x 32 chunks = 1024, 8/thread (conflict-free)
        #pragma unroll
        for (int j = 0; j < 8; ++j) {
            int it = tid + j * 128;
            int n = it >> 5, cq = it & 31;
            *(float4*)&Ks[n * 264 + cq * 8] =
                *(const float4*)&f1r[(((size_t)b * N_ + n0 + n) << 8) + cq * 8];
        }
        __syncthreads();

        // QK^T (swapped): S rows = n (reg pattern), col = m = rl
        f32x16 S;
        #pragma unroll
        for (int e = 0; e < 16; ++e) S[e] = 0.f;
        __builtin_amdgcn_s_setprio(1);
        #pragma unroll
        for (int st = 0; st < 16; ++st) {
            bf16x8 Kf = *(const bf16x8*)&Ks[rl * 264 + st * 16 + l5 * 8];
            S = __builtin_amdgcn_mfma_f32_32x32x16_bf16(Kf, Qf[st], S, 0, 0, 0);
        }
        __builtin_amdgcn_s_setprio(0);

        // issue direct V loads for this tile (L2 hits; latency hides under softmax)
        bf16x8 Vf0[4], Vf1[4];
        #pragma unroll
        for (int cf = 0; cf < 4; ++cf) {
            const unsigned short* vr = vbase + ((size_t)(cf * 32) << 12) + n0 + l5 * 8;
            Vf0[cf] = *(const bf16x8*)vr;
            Vf1[cf] = *(const bf16x8*)(vr + 16);
        }

        // online softmax for m = rl over the tile's 32 n
        float mx = S[0];
        #pragma unroll
        for (int e = 1; e < 16; ++e) mx = fmaxf(mx, S[e]);
        mx = fmaxf(mx, __shfl_xor(mx, 32));

        // defer-max: rescale only when the max grew past THR=8
        if (!__all(mx <= m_run + 8.f)) {
            float m_new = fmaxf(m_run, mx);
            float sc = __expf(m_run - m_new);
            l_run *= sc;
            #pragma unroll
            for (int cf = 0; cf < 4; ++cf)
                #pragma unroll
                for (int e = 0; e < 16; ++e) O[cf][e] *= sc;
            m_run = m_new;
        }

        float p[16]; float lsum = 0.f;
        #pragma unroll
        for (int e = 0; e < 16; ++e) { p[e] = __expf(S[e] - m_run); lsum += p[e]; }
        l_run += lsum;

        // P -> bf16 B-frags (row m = rl, k = n-local). n(reg r) = (r&3)+8*(r>>2)+4*l5
        unsigned pk_[8], xk[8];
        #pragma unroll
        for (int g = 0; g < 8; ++g)
            pk_[g] = (unsigned)f2bf(p[2 * g]) | ((unsigned)f2bf(p[2 * g + 1]) << 16);
        #pragma unroll
        for (int g = 0; g < 8; ++g) xk[g] = (unsigned)__shfl_xor((int)pk_[g], 32);
        union { unsigned d[4]; bf16x8 v; } P0, P1;
        P0.d[0] = l5 ? xk[2] : pk_[0];
        P0.d[1] = l5 ? xk[3] : pk_[1];
        P0.d[2] = l5 ? pk_[2] : xk[0];
        P0.d[3] = l5 ? pk_[3] : xk[1];
        P1.d[0] = l5 ? xk[6] : pk_[4];
        P1.d[1] = l5 ? xk[7] : pk_[5];
        P1.d[2] = l5 ? pk_[6] : xk[4];
        P1.d[3] = l5 ? pk_[7] : xk[5];

        // PV: A = V^T rows c (direct-from-global frags), B = P rows m
        __builtin_amdgcn_s_setprio(1);
        #pragma unroll
        for (int cf = 0; cf < 4; ++cf) {
            O[cf] = __builtin_amdgcn_mfma_f32_32x32x16_bf16(Vf0[cf], P0.v, O[cf], 0, 0, 0);
            O[cf] = __builtin_amdgcn_mfma_f32_32x32x16_bf16(Vf1[cf], P1.v, O[cf], 0, 0, 0);
        }
        __builtin_amdgcn_s_setprio(0);
        __syncthreads();
    }

    // epilogue: unnormalized partial (bf16) + stats
    float l_tot = l_run + __shfl_xor(l_run, 32);
    const int se = s;
    unsigned short* pb = part + (size_t)se * ((size_t)B_ * C_ * N_);
    #pragma unroll
    for (int cf = 0; cf < 4; ++cf)
        #pragma unroll
        for (int e = 0; e < 16; ++e) {
            int c = c0w + cf * 32 + (e & 3) + 8 * (e >> 2) + 4 * l5;
            pb[(((size_t)b * C_ + c) << 12) + m0 + rl] = f2bf(O[cf][e]);
        }
    if (wc2 == 0 && l5 == 0) {
        float2 st; st.x = m_run; st.y = l_tot;
        ((float2*)stats)[(((size_t)(se * 2 + b)) << 12) + m0 + rl] = st;
    }
}

// ---------------------------------------------------------------------------
// Combine: out[b][c][m] = gamma * (sum_se w_se*part_se) / (sum_se w_se*l_se) + x
// part is bf16 (all-positive; relative error ~0.4% cancels in num/den).
// ---------------------------------------------------------------------------
__global__ __launch_bounds__(256) void combine_k(
    const unsigned short* __restrict__ part, const float* __restrict__ stats,
    const float* __restrict__ x, const float* __restrict__ gamma,
    float* __restrict__ out)
{
    const float g = gamma[0];
    size_t i = (size_t)blockIdx.x * 256 + threadIdx.x;
    size_t idx = i << 2;
    const int m = (int)(idx & 4095);
    const int b = (int)(idx >> 20);              // /(C*N)=2^20
    const size_t PS = (size_t)B_ * C_ * N_;

    float ms[4][4], ls[4][4];
    #pragma unroll
    for (int se = 0; se < 4; ++se) {
        const float2* sp = (const float2*)stats + (((size_t)(se * 2 + b)) << 12) + m;
        #pragma unroll
        for (int j = 0; j < 4; ++j) { float2 v = sp[j]; ms[se][j] = v.x; ls[se][j] = v.y; }
    }
    float w[4][4], den[4] = {0.f, 0.f, 0.f, 0.f};
    #pragma unroll
    for (int j = 0; j < 4; ++j) {
        float M = fmaxf(fmaxf(ms[0][j], ms[1][j]), fmaxf(ms[2][j], ms[3][j]));
        #pragma unroll
        for (int se = 0; se < 4; ++se) {
            w[se][j] = __expf(ms[se][j] - M);
            den[j] += w[se][j] * ls[se][j];
        }
    }
    float num[4] = {0.f, 0.f, 0.f, 0.f};
    #pragma unroll
    for (int se = 0; se < 4; ++se) {
        ushort4 u = *(const ushort4*)&part[se * PS + idx];
        num[0] += w[se][0] * bf2f(u.x); num[1] += w[se][1] * bf2f(u.y);
        num[2] += w[se][2] * bf2f(u.z); num[3] += w[se][3] * bf2f(u.w);
    }
    float4 xv = ((const float4*)x)[i];
    float4 o;
    o.x = g * num[0] / den[0] + xv.x;
    o.y = g * num[1] / den[1] + xv.y;
    o.z = g * num[2] / den[2] + xv.z;
    o.w = g * num[3] / den[3] + xv.w;
    ((float4*)out)[i] = o;
}

extern "C" void kernel_launch(void* const* d_in, const int* in_sizes, int n_in,
                              void* d_out, int out_size, void* d_ws, size_t ws_size,
                              hipStream_t stream) {
    const float* x     = (const float*)d_in[0];
    const float* ref_x = (const float*)d_in[1];
    const float* w1    = (const float*)d_in[2];
    const float* b1    = (const float*)d_in[3];
    const float* w2    = (const float*)d_in[4];
    const float* b2    = (const float*)d_in[5];
    const float* gamma = (const float*)d_in[6];
    float* out = (float*)d_out;

    char* ws = (char*)d_ws;
    size_t off = 0;
    auto nxt = [&](size_t bytes) {
        char* p = ws + off;
        off += (bytes + 255) & ~(size_t)255;
        return p;
    };
    unsigned short* f1x = (unsigned short*)nxt((size_t)B_ * N_ * C_ * 2);  // bf16 [b][m][c]
    unsigned short* f1r = (unsigned short*)nxt((size_t)B_ * N_ * C_ * 2);  // bf16 [b][n][c]
    unsigned short* f2  = (unsigned short*)nxt((size_t)B_ * N_ * C_ * 2);  // bf16 [b][c][n]
    unsigned short* xtx = (unsigned short*)nxt((size_t)B_ * N_ * C_ * 2);  // fp16 [b][p][c]
    unsigned short* xtr = (unsigned short*)nxt((size_t)B_ * N_ * C_ * 2);  // fp16 [b][p][c]
    unsigned short* w1h = (unsigned short*)nxt((size_t)9 * C_ * C_ * 2);   // fp16 [tap][o][i]
    unsigned short* w2h = (unsigned short*)nxt((size_t)9 * C_ * C_ * 2);   // fp16 [tap][o][i]
    unsigned short* part = (unsigned short*)nxt((size_t)4 * B_ * C_ * N_ * 2); // bf16, 16.8 MB
    float* stats = (float*)nxt((size_t)4 * B_ * N_ * 8);                   // float2

    prep_k<<<5632, 256, 0, stream>>>(x, ref_x, w1, w2, xtx, xtr, w1h, w2h);

    conv_mfma_k<<<dim3(32, 4, 6), 256, 0, stream>>>(xtx, xtr, w1h, w2h, b1, b2,
                                                    f1x, f1r, f2);

    flash_k<<<dim3(128, 4, 2), 128, 0, stream>>>(f1x, f1r, f2, part, stats);
    combine_k<<<2048, 256, 0, stream>>>(part, stats, x, gamma, out);
}

// Round 20
// 145.183 us; speedup vs baseline: 1.0554x; 1.0554x over previous
//
#include <hip/hip_runtime.h>
#include <hip/hip_bf16.h>

#define B_ 2
#define C_ 256
#define H_ 64
#define W_ 64
#define N_ 4096  // H_*W_

typedef short bf16x8 __attribute__((ext_vector_type(8)));
typedef _Float16 f16x8 __attribute__((ext_vector_type(8)));
typedef float f32x4 __attribute__((ext_vector_type(4)));
typedef float f32x16 __attribute__((ext_vector_type(16)));

// float -> bf16 (round to nearest even), finite inputs
static __device__ __forceinline__ unsigned short f2bf(float f) {
    union { float f; unsigned u; } uf; uf.f = f;
    unsigned r = uf.u + 0x7fffu + ((uf.u >> 16) & 1u);
    return (unsigned short)(r >> 16);
}
// bf16 bits -> float
static __device__ __forceinline__ float bf2f(unsigned short us) {
    union { unsigned u; float f; } c; c.u = ((unsigned)us) << 16; return c.f;
}
// float -> fp16 bits
static __device__ __forceinline__ unsigned short f2h_u(float f) {
    union { _Float16 h; unsigned short u; } c; c.h = (_Float16)f; return c.u;
}

// async global->LDS, 16B per lane. LDS dest must be wave-uniform base + lane*16.
static __device__ __forceinline__ void gload16(const void* g, void* l) {
    __builtin_amdgcn_global_load_lds(
        (const __attribute__((address_space(1))) unsigned int*)g,
        (__attribute__((address_space(3))) unsigned int*)l, 16, 0, 0);
}

// ---------------------------------------------------------------------------
// Prep (merged): blocks [0,1024): [B][C][N] f32 -> [B][N][C] fp16 transpose
// for x and ref_x; blocks [1024,5632): both weights -> [tap][O][I] fp16.
// ---------------------------------------------------------------------------
__global__ __launch_bounds__(256) void prep_k(
    const float* __restrict__ x, const float* __restrict__ ref_x,
    const float* __restrict__ w1, const float* __restrict__ w2,
    unsigned short* __restrict__ xtx, unsigned short* __restrict__ xtr,
    unsigned short* __restrict__ wh1, unsigned short* __restrict__ wh2)
{
    __shared__ unsigned short t[64][72];
    const int bx = blockIdx.x;
    if (bx < 1024) {
        const int pt = bx & 63, ct = (bx >> 6) & 3;
        const int z = bx >> 8;
        const int which = z >> 1, b = z & 1;
        const float* in = which ? ref_x : x;
        unsigned short* out = which ? xtr : xtx;
        const int a = threadIdx.x & 63, r = threadIdx.x >> 6;
        #pragma unroll
        for (int i = 0; i < 16; ++i) {
            int c = i * 4 + r;
            t[c][a] = f2h_u(in[((size_t)(b * C_ + ct * 64 + c) << 12) + pt * 64 + a]);
        }
        __syncthreads();
        #pragma unroll
        for (int i = 0; i < 16; ++i) {
            int p = i * 4 + r;
            out[((size_t)(b * N_ + pt * 64 + p) << 8) + ct * 64 + a] = t[a][p];
        }
    } else {
        int g = bx - 1024;
        const float* w = (g < 2304) ? w1 : w2;
        unsigned short* wh = (g < 2304) ? wh1 : wh2;
        int i = (g % 2304) * 256 + threadIdx.x;     // < 9*256*256 exactly
        int ci = i & 255, co = (i >> 8) & 255, tap = i >> 16;
        wh[i] = f2h_u(w[((size_t)(co * 256 + ci)) * 9 + tap]);
    }
}

// ---------------------------------------------------------------------------
// Implicit-GEMM 3x3 SAME conv + bias + relu via MFMA fp16 (r4-proven version).
// ---------------------------------------------------------------------------
__global__ __launch_bounds__(256) void conv_mfma_k(
    const unsigned short* __restrict__ xtx, const unsigned short* __restrict__ xtr,
    const unsigned short* __restrict__ w1h, const unsigned short* __restrict__ w2h,
    const float* __restrict__ b1, const float* __restrict__ b2,
    unsigned short* __restrict__ f1x, unsigned short* __restrict__ f1r,
    unsigned short* __restrict__ f2)
{
    __shared__ unsigned short As[4 * 576 * 8];   // (q*576 + tap*64 + co)*8
    __shared__ unsigned short Bs[4 * 66 * 32];   // [row][col(pad)][ci-chunk swz]
    const int tid = threadIdx.x;
    const int pt  = blockIdx.x;   // 0..31 : plane rows pt*2, pt*2+1
    const int cot = blockIdx.y;   // 0..3
    const int cid = blockIdx.z >> 1;
    const int b   = blockIdx.z & 1;

    const unsigned short* xt = (cid == 1) ? xtr : xtx;
    const unsigned short* wt = (cid == 2) ? w2h : w1h;
    const float* bias = (cid == 2) ? b2 : b1;
    unsigned short* out = (cid == 0) ? f1x : (cid == 1) ? f1r : f2;
    const int trans = (cid != 2);

    const int lane = tid & 63, wid = tid >> 6;
    const int wco = wid >> 1, wpos = wid & 1;
    const int rl = lane & 15, q = lane >> 4;
    const int r0 = pt * 2;

    f32x4 acc[2][4];
    #pragma unroll
    for (int mi = 0; mi < 2; ++mi)
        #pragma unroll
        for (int ni = 0; ni < 4; ++ni)
            #pragma unroll
            for (int e = 0; e < 4; ++e) acc[mi][ni][e] = 0.f;

    for (int k0 = 0; k0 < C_; k0 += 32) {
        #pragma unroll
        for (int tap = 0; tap < 9; ++tap) {
            gload16(wt + ((size_t)(tap * C_ + cot * 64 + lane) << 8) + k0 + wid * 8,
                    &As[(wid * 576 + tap * 64 + lane) * 8]);
        }
        #pragma unroll
        for (int j = 0; j < 5; ++j) {
            int it = tid + j * 256;
            if (it < 1056) {
                int col = it >> 4, sub = it & 15;
                int row = sub >> 2, qb = sub & 3;
                int h = r0 + row - 1, c = col - 1;
                float4 v; v.x = 0.f; v.y = 0.f; v.z = 0.f; v.w = 0.f;
                if (h >= 0 && h < 64 && c >= 0 && c < 64)
                    v = *(const float4*)(xt + ((size_t)(b * N_ + h * 64 + c) << 8) + k0 + qb * 8);
                int chunk = qb ^ ((col >> 1) & 3);
                *(float4*)&Bs[(row * 66 + col) * 32 + chunk * 8] = v;
            }
        }
        __syncthreads();

        #pragma unroll
        for (int tap = 0; tap < 9; ++tap) {
            const int kh = tap / 3, kw = tap % 3;
            f16x8 a0 = *(const f16x8*)&As[(q * 576 + tap * 64 + wco * 32 + rl) * 8];
            f16x8 a1 = *(const f16x8*)&As[(q * 576 + tap * 64 + wco * 32 + 16 + rl) * 8];
            const int chunkB = q ^ (((rl + kw) >> 1) & 3);
            const int rowB = (wpos + kh) * 66;
            #pragma unroll
            for (int ni = 0; ni < 4; ++ni) {
                int colB = ni * 16 + rl + kw;
                f16x8 bf = *(const f16x8*)&Bs[(rowB + colB) * 32 + chunkB * 8];
                acc[0][ni] = __builtin_amdgcn_mfma_f32_16x16x32_f16(a0, bf, acc[0][ni], 0, 0, 0);
                acc[1][ni] = __builtin_amdgcn_mfma_f32_16x16x32_f16(a1, bf, acc[1][ni], 0, 0, 0);
            }
        }
        __syncthreads();
    }

    #pragma unroll
    for (int mi = 0; mi < 2; ++mi) {
        const int co = cot * 64 + wco * 32 + mi * 16 + q * 4;
        float bs[4];
        #pragma unroll
        for (int rr = 0; rr < 4; ++rr) bs[rr] = bias[co + rr];
        #pragma unroll
        for (int ni = 0; ni < 4; ++ni) {
            const int pos = pt * 128 + wpos * 64 + ni * 16 + rl;
            if (trans) {
                unsigned short pk[4];
                #pragma unroll
                for (int rr = 0; rr < 4; ++rr)
                    pk[rr] = f2bf(fmaxf(acc[mi][ni][rr] + bs[rr], 0.f));
                uint2 u;
                u.x = (unsigned)pk[0] | ((unsigned)pk[1] << 16);
                u.y = (unsigned)pk[2] | ((unsigned)pk[3] << 16);
                *(uint2*)&out[((size_t)(b * N_ + pos) << 8) + co] = u;
            } else {
                #pragma unroll
                for (int rr = 0; rr < 4; ++rr)
                    out[((size_t)(b * C_ + co + rr) << 12) + pos] =
                        f2bf(fmaxf(acc[mi][ni][rr] + bs[rr], 0.f));
            }
        }
    }
}

// ---------------------------------------------------------------------------
// Flash attention v3 (r15/r18-proven): KVBLK=32, 128-thread blocks (2 waves,
// wc2 c-split), 37.4 KB LDS -> 4 blocks/CU, bf16 partials. LDS-staged V
// (direct-from-global variant was uncoalesced and slower — r19).
// Grid (128 mt, 4 s, 2 b) = 1024 blocks. se = s -> 4 partials.
// ---------------------------------------------------------------------------
__global__ __launch_bounds__(128, 2) void flash_k(
    const unsigned short* __restrict__ f1x,  // Q  [b][m][ch] bf16
    const unsigned short* __restrict__ f1r,  // K  [b][n][ch] bf16
    const unsigned short* __restrict__ f2,   // V^T [b][c][n] bf16
    unsigned short* __restrict__ part,       // [4][B][C][N] bf16
    float* __restrict__ stats)               // float2 [4][B][N]
{
    __shared__ unsigned short Ks[32 * 264];  // [n32][256ch + 8 pad]
    __shared__ unsigned short Vs[256 * 40];  // [c256][32n + 8 pad]
    const int tid = threadIdx.x;             // 0..127
    const int mt = blockIdx.x, s = blockIdx.y, b = blockIdx.z;
    const int m0 = mt * 32;
    const int lane = tid & 63, wc2 = tid >> 6;
    const int rl = lane & 31, l5 = lane >> 5;
    const int c0w = wc2 * 128;

    // Q B-frags for 16 ch-steps (row m = rl, k = l5*8+j)
    bf16x8 Qf[16];
    #pragma unroll
    for (int st = 0; st < 16; ++st)
        Qf[st] = *(const bf16x8*)&f1x[(((size_t)b * N_ + m0 + rl) << 8) + st * 16 + l5 * 8];

    f32x16 O[4];
    #pragma unroll
    for (int cf = 0; cf < 4; ++cf)
        #pragma unroll
        for (int e = 0; e < 16; ++e) O[cf][e] = 0.f;
    float m_run = -1e30f, l_run = 0.f;

    const int nbase = s * 1024;
    for (int r = 0; r < 32; ++r) {
        const int n0 = nbase + r * 32;
        // stage K: 32 rows x 32 chunks = 1024, 8/thread
        #pragma unroll
        for (int j = 0; j < 8; ++j) {
            int it = tid + j * 128;
            int n = it >> 5, cq = it & 31;
            *(float4*)&Ks[n * 264 + cq * 8] =
                *(const float4*)&f1r[(((size_t)b * N_ + n0 + n) << 8) + cq * 8];
        }
        // stage V: 256 rows x 4 chunks = 1024, 8/thread
        #pragma unroll
        for (int j = 0; j < 8; ++j) {
            int it = tid + j * 128;
            int c = it >> 2, nq = it & 3;
            *(float4*)&Vs[c * 40 + nq * 8] =
                *(const float4*)&f2[(((size_t)b * C_ + c) << 12) + n0 + nq * 8];
        }
        __syncthreads();

        // QK^T (swapped): S rows = n (reg pattern), col = m = rl
        f32x16 S;
        #pragma unroll
        for (int e = 0; e < 16; ++e) S[e] = 0.f;
        __builtin_amdgcn_s_setprio(1);
        #pragma unroll
        for (int st = 0; st < 16; ++st) {
            bf16x8 Kf = *(const bf16x8*)&Ks[rl * 264 + st * 16 + l5 * 8];
            S = __builtin_amdgcn_mfma_f32_32x32x16_bf16(Kf, Qf[st], S, 0, 0, 0);
        }
        __builtin_amdgcn_s_setprio(0);

        // online softmax for m = rl over the tile's 32 n
        float mx = S[0];
        #pragma unroll
        for (int e = 1; e < 16; ++e) mx = fmaxf(mx, S[e]);
        mx = fmaxf(mx, __shfl_xor(mx, 32));

        // defer-max: rescale only when the max grew past THR=8
        if (!__all(mx <= m_run + 8.f)) {
            float m_new = fmaxf(m_run, mx);
            float sc = __expf(m_run - m_new);
            l_run *= sc;
            #pragma unroll
            for (int cf = 0; cf < 4; ++cf)
                #pragma unroll
                for (int e = 0; e < 16; ++e) O[cf][e] *= sc;
            m_run = m_new;
        }

        float p[16]; float lsum = 0.f;
        #pragma unroll
        for (int e = 0; e < 16; ++e) { p[e] = __expf(S[e] - m_run); lsum += p[e]; }
        l_run += lsum;

        // P -> bf16 B-frags (row m = rl, k = n-local). n(reg r) = (r&3)+8*(r>>2)+4*l5
        unsigned pk_[8], xk[8];
        #pragma unroll
        for (int g = 0; g < 8; ++g)
            pk_[g] = (unsigned)f2bf(p[2 * g]) | ((unsigned)f2bf(p[2 * g + 1]) << 16);
        #pragma unroll
        for (int g = 0; g < 8; ++g) xk[g] = (unsigned)__shfl_xor((int)pk_[g], 32);
        union { unsigned d[4]; bf16x8 v; } P0, P1;
        P0.d[0] = l5 ? xk[2] : pk_[0];
        P0.d[1] = l5 ? xk[3] : pk_[1];
        P0.d[2] = l5 ? pk_[2] : xk[0];
        P0.d[3] = l5 ? pk_[3] : xk[1];
        P1.d[0] = l5 ? xk[6] : pk_[4];
        P1.d[1] = l5 ? xk[7] : pk_[5];
        P1.d[2] = l5 ? pk_[6] : xk[4];
        P1.d[3] = l5 ? pk_[7] : xk[5];

        // PV: A = V^T rows c (this wave's 128), B = P rows m -> O rows c, col m
        __builtin_amdgcn_s_setprio(1);
        #pragma unroll
        for (int cf = 0; cf < 4; ++cf) {
            const int vrow = (c0w + cf * 32 + rl) * 40;
            bf16x8 Vf0 = *(const bf16x8*)&Vs[vrow + l5 * 8];
            O[cf] = __builtin_amdgcn_mfma_f32_32x32x16_bf16(Vf0, P0.v, O[cf], 0, 0, 0);
            bf16x8 Vf1 = *(const bf16x8*)&Vs[vrow + 16 + l5 * 8];
            O[cf] = __builtin_amdgcn_mfma_f32_32x32x16_bf16(Vf1, P1.v, O[cf], 0, 0, 0);
        }
        __builtin_amdgcn_s_setprio(0);
        __syncthreads();
    }

    // epilogue: unnormalized partial (bf16) + stats
    float l_tot = l_run + __shfl_xor(l_run, 32);
    const int se = s;
    unsigned short* pb = part + (size_t)se * ((size_t)B_ * C_ * N_);
    #pragma unroll
    for (int cf = 0; cf < 4; ++cf)
        #pragma unroll
        for (int e = 0; e < 16; ++e) {
            int c = c0w + cf * 32 + (e & 3) + 8 * (e >> 2) + 4 * l5;
            pb[(((size_t)b * C_ + c) << 12) + m0 + rl] = f2bf(O[cf][e]);
        }
    if (wc2 == 0 && l5 == 0) {
        float2 st; st.x = m_run; st.y = l_tot;
        ((float2*)stats)[(((size_t)(se * 2 + b)) << 12) + m0 + rl] = st;
    }
}

// ---------------------------------------------------------------------------
// Combine: out[b][c][m] = gamma * (sum_se w_se*part_se) / (sum_se w_se*l_se) + x
// part is bf16 (all-positive; relative error ~0.4% cancels in num/den).
// ---------------------------------------------------------------------------
__global__ __launch_bounds__(256) void combine_k(
    const unsigned short* __restrict__ part, const float* __restrict__ stats,
    const float* __restrict__ x, const float* __restrict__ gamma,
    float* __restrict__ out)
{
    const float g = gamma[0];
    size_t i = (size_t)blockIdx.x * 256 + threadIdx.x;
    size_t idx = i << 2;
    const int m = (int)(idx & 4095);
    const int b = (int)(idx >> 20);              // /(C*N)=2^20
    const size_t PS = (size_t)B_ * C_ * N_;

    float ms[4][4], ls[4][4];
    #pragma unroll
    for (int se = 0; se < 4; ++se) {
        const float2* sp = (const float2*)stats + (((size_t)(se * 2 + b)) << 12) + m;
        #pragma unroll
        for (int j = 0; j < 4; ++j) { float2 v = sp[j]; ms[se][j] = v.x; ls[se][j] = v.y; }
    }
    float w[4][4], den[4] = {0.f, 0.f, 0.f, 0.f};
    #pragma unroll
    for (int j = 0; j < 4; ++j) {
        float M = fmaxf(fmaxf(ms[0][j], ms[1][j]), fmaxf(ms[2][j], ms[3][j]));
        #pragma unroll
        for (int se = 0; se < 4; ++se) {
            w[se][j] = __expf(ms[se][j] - M);
            den[j] += w[se][j] * ls[se][j];
        }
    }
    float num[4] = {0.f, 0.f, 0.f, 0.f};
    #pragma unroll
    for (int se = 0; se < 4; ++se) {
        ushort4 u = *(const ushort4*)&part[se * PS + idx];
        num[0] += w[se][0] * bf2f(u.x); num[1] += w[se][1] * bf2f(u.y);
        num[2] += w[se][2] * bf2f(u.z); num[3] += w[se][3] * bf2f(u.w);
    }
    float4 xv = ((const float4*)x)[i];
    float4 o;
    o.x = g * num[0] / den[0] + xv.x;
    o.y = g * num[1] / den[1] + xv.y;
    o.z = g * num[2] / den[2] + xv.z;
    o.w = g * num[3] / den[3] + xv.w;
    ((float4*)out)[i] = o;
}

extern "C" void kernel_launch(void* const* d_in, const int* in_sizes, int n_in,
                              void* d_out, int out_size, void* d_ws, size_t ws_size,
                              hipStream_t stream) {
    const float* x     = (const float*)d_in[0];
    const float* ref_x = (const float*)d_in[1];
    const float* w1    = (const float*)d_in[2];
    const float* b1    = (const float*)d_in[3];
    const float* w2    = (const float*)d_in[4];
    const float* b2    = (const float*)d_in[5];
    const float* gamma = (const float*)d_in[6];
    float* out = (float*)d_out;

    char* ws = (char*)d_ws;
    size_t off = 0;
    auto nxt = [&](size_t bytes) {
        char* p = ws + off;
        off += (bytes + 255) & ~(size_t)255;
        return p;
    };
    unsigned short* f1x = (unsigned short*)nxt((size_t)B_ * N_ * C_ * 2);  // bf16 [b][m][c]
    unsigned short* f1r = (unsigned short*)nxt((size_t)B_ * N_ * C_ * 2);  // bf16 [b][n][c]
    unsigned short* f2  = (unsigned short*)nxt((size_t)B_ * N_ * C_ * 2);  // bf16 [b][c][n]
    unsigned short* xtx = (unsigned short*)nxt((size_t)B_ * N_ * C_ * 2);  // fp16 [b][p][c]
    unsigned short* xtr = (unsigned short*)nxt((size_t)B_ * N_ * C_ * 2);  // fp16 [b][p][c]
    unsigned short* w1h = (unsigned short*)nxt((size_t)9 * C_ * C_ * 2);   // fp16 [tap][o][i]
    unsigned short* w2h = (unsigned short*)nxt((size_t)9 * C_ * C_ * 2);   // fp16 [tap][o][i]
    unsigned short* part = (unsigned short*)nxt((size_t)4 * B_ * C_ * N_ * 2); // bf16, 16.8 MB
    float* stats = (float*)nxt((size_t)4 * B_ * N_ * 8);                   // float2

    prep_k<<<5632, 256, 0, stream>>>(x, ref_x, w1, w2, xtx, xtr, w1h, w2h);

    conv_mfma_k<<<dim3(32, 4, 6), 256, 0, stream>>>(xtx, xtr, w1h, w2h, b1, b2,
                                                    f1x, f1r, f2);

    flash_k<<<dim3(128, 4, 2), 128, 0, stream>>>(f1x, f1r, f2, part, stats);
    combine_k<<<2048, 256, 0, stream>>>(part, stats, x, gamma, out);
}